// Round 9
// baseline (367.332 us; speedup 1.0000x reference)
//
#include <hip/hip_runtime.h>
#include <math.h>

// Problem constants (B=4, S=1024, E=512, H=8, D=64, T_MAX=20)
#define SEQ   1024
#define EMB   512
#define NROWS 4096   // B*S
#define LDP   72     // attn LDS row stride (bf16 elems)
#define GROWS 8      // gates rows per block

typedef __attribute__((ext_vector_type(8))) short short8;    // bf16 x8 MFMA frag
typedef __attribute__((ext_vector_type(4))) float float4v;   // f32 x4 MFMA acc

__device__ __forceinline__ float bf2f(unsigned short s) {
    union { float f; unsigned u; } x; x.u = ((unsigned)s) << 16; return x.f;
}
__device__ __forceinline__ unsigned short f2bf(float f) {
    union { float f; unsigned u; } x; x.f = f;
    unsigned r = x.u + 0x7fffu + ((x.u >> 16) & 1u);   // round-to-nearest-even
    return (unsigned short)(r >> 16);
}
// 3-way bf16 split: v ~= h + m + l, residual <= 2^-27 |v|
__device__ __forceinline__ void split3(float v, unsigned short& h, unsigned short& m, unsigned short& l) {
    h = f2bf(v);
    float r1 = v - bf2f(h);
    m = f2bf(r1);
    float r2 = r1 - bf2f(m);
    l = f2bf(r2);
}

// ---------------------------------------------------------------------------
// K0: gate + complexity MLPs -> T_i[4096]. 8 rows per block. All-f32.
// ---------------------------------------------------------------------------
template<int H1, int H2>
__device__ __forceinline__ float gate_mlp_block(
    const float xs[GROWS][EMB], float h1[GROWS][128], float h2[GROWS][64],
    float* mu_s, float* var_s,
    const float* __restrict__ W1, const float* __restrict__ b1,
    const float* __restrict__ gam, const float* __restrict__ bet,
    const float* __restrict__ W2, const float* __restrict__ b2,
    const float* __restrict__ W3, const float* __restrict__ b3,
    int tid, int myrow)
{
    constexpr int RN1 = GROWS * H1 / 256;
    constexpr int RN2 = GROWS * H2 / 256;

    {   // h1 = x @ W1 + b1
        const int col = tid % H1;
        const int rb  = (tid / H1) * RN1;
        float acc[RN1];
        #pragma unroll
        for (int r = 0; r < RN1; ++r) acc[r] = b1[col];
        for (int k = 0; k < EMB; ++k) {
            const float w = W1[k * H1 + col];
            #pragma unroll
            for (int r = 0; r < RN1; ++r) acc[r] += w * xs[rb + r][k];
        }
        #pragma unroll
        for (int r = 0; r < RN1; ++r) h1[rb + r][col] = acc[r];
    }
    __syncthreads();

    {   // mean
        const int r = tid >> 5, l = tid & 31;
        float s = 0.f;
        for (int c = l; c < H1; c += 32) s += h1[r][c];
        #pragma unroll
        for (int off = 16; off >= 1; off >>= 1) s += __shfl_xor(s, off);
        if (l == 0) mu_s[r] = s / (float)H1;
    }
    __syncthreads();
    {   // var
        const int r = tid >> 5, l = tid & 31;
        const float mu = mu_s[r];
        float s = 0.f;
        for (int c = l; c < H1; c += 32) { const float d = h1[r][c] - mu; s += d * d; }
        #pragma unroll
        for (int off = 16; off >= 1; off >>= 1) s += __shfl_xor(s, off);
        if (l == 0) var_s[r] = s / (float)H1;
    }
    __syncthreads();
    for (int idx = tid; idx < GROWS * H1; idx += 256) {
        const int r = idx / H1, cc = idx % H1;
        float hn = (h1[r][cc] - mu_s[r]) / sqrtf(var_s[r] + 1e-5f) * gam[cc] + bet[cc];
        h1[r][cc] = hn > 0.f ? hn : 0.f;
    }
    __syncthreads();

    {   // h2 = relu(h1 @ W2 + b2)
        const int col = tid % H2;
        const int rb  = (tid / H2) * RN2;
        float acc[RN2];
        #pragma unroll
        for (int r = 0; r < RN2; ++r) acc[r] = b2[col];
        for (int k = 0; k < H1; ++k) {
            const float w = W2[k * H2 + col];
            #pragma unroll
            for (int r = 0; r < RN2; ++r) acc[r] += w * h1[rb + r][k];
        }
        #pragma unroll
        for (int r = 0; r < RN2; ++r) h2[rb + r][col] = acc[r] > 0.f ? acc[r] : 0.f;
    }
    __syncthreads();

    {   // scalar = h2 @ W3
        const int r = tid >> 5, l = tid & 31;
        float s = 0.f;
        for (int c = l; c < H2; c += 32) s += h2[r][c] * W3[c];
        #pragma unroll
        for (int off = 16; off >= 1; off >>= 1) s += __shfl_xor(s, off);
        if (l == 0) mu_s[r] = s;
    }
    __syncthreads();
    float ret = 0.f;
    if (myrow >= 0) {
        const float z = mu_s[myrow] + b3[0];
        ret = 1.0f / (1.0f + expf(-z));
    }
    __syncthreads();
    return ret;
}

__global__ __launch_bounds__(256) void gates_kernel(
    const float* __restrict__ x,
    const float* __restrict__ gW1, const float* __restrict__ gb1,
    const float* __restrict__ gg,  const float* __restrict__ gbe,
    const float* __restrict__ gW2, const float* __restrict__ gb2,
    const float* __restrict__ gW3, const float* __restrict__ gb3,
    const float* __restrict__ cW1, const float* __restrict__ cb1,
    const float* __restrict__ cg,  const float* __restrict__ cbe,
    const float* __restrict__ cW2, const float* __restrict__ cb2,
    const float* __restrict__ cW3, const float* __restrict__ cb3,
    int* __restrict__ T_i)
{
    __shared__ float xs[GROWS][EMB];
    __shared__ float h1[GROWS][128];
    __shared__ float h2[GROWS][64];
    __shared__ float mu_s[GROWS], var_s[GROWS];

    const int row0 = blockIdx.x * GROWS;
    const int tid = threadIdx.x;

    for (int idx = tid; idx < GROWS * EMB; idx += 256) {
        const int r = idx >> 9, cc = idx & 511;
        xs[r][cc] = x[(size_t)(row0 + r) * EMB + cc];
    }
    __syncthreads();

    const int myrow = (tid < GROWS) ? tid : -1;
    const float g0 = gate_mlp_block<128, 64>(xs, h1, h2, mu_s, var_s,
                                             gW1, gb1, gg, gbe, gW2, gb2, gW3, gb3, tid, myrow);
    const float c0 = gate_mlp_block<64, 32>(xs, h1, h2, mu_s, var_s,
                                            cW1, cb1, cg, cbe, cW2, cb2, cW3, cb3, tid, myrow);

    if (tid < GROWS) {
        const int row = row0 + tid;
        const int s = row & (SEQ - 1);
        const float step = (1.2f - 0.8f) / (float)(SEQ - 1);
        const float pos  = (float)s * step + 0.8f;
        const float score = ((1.0f - 0.3f) * g0 + 0.3f * c0) * pos;
        float t = ceilf(score * 20.0f);
        t = t < 1.f ? 1.f : (t > 20.f ? 20.f : t);
        T_i[row] = (int)t;
    }
}

// ---------------------------------------------------------------------------
// K1a: split x into 3 bf16 arrays (elementwise).
// ---------------------------------------------------------------------------
__global__ __launch_bounds__(256) void split_x_kernel(
    const float* __restrict__ src,
    unsigned short* __restrict__ xh, unsigned short* __restrict__ xm,
    unsigned short* __restrict__ xl)
{
    const int i4 = (blockIdx.x * 256 + threadIdx.x) * 4;
    const float4 v = *(const float4*)&src[i4];
    ushort4 h4, m4, l4;
    split3(v.x, h4.x, m4.x, l4.x);
    split3(v.y, h4.y, m4.y, l4.y);
    split3(v.z, h4.z, m4.z, l4.z);
    split3(v.w, h4.w, m4.w, l4.w);
    *(ushort4*)&xh[i4] = h4;
    *(ushort4*)&xm[i4] = m4;
    *(ushort4*)&xl[i4] = l4;
}

// ---------------------------------------------------------------------------
// K1b: transpose + 3-way split Wq/Wk/Wv (z = blockIdx.z selects the weight).
// ---------------------------------------------------------------------------
__global__ __launch_bounds__(256) void split_wt_kernel(
    const float* __restrict__ Wq, const float* __restrict__ Wk,
    const float* __restrict__ Wv,
    unsigned short* __restrict__ th, unsigned short* __restrict__ tm,
    unsigned short* __restrict__ tl)
{
    __shared__ float Ws[64][65];
    const int z = blockIdx.z;
    const float* __restrict__ W = (z == 0) ? Wq : (z == 1) ? Wk : Wv;
    const size_t obase = (size_t)z * EMB * EMB;
    const int k0 = blockIdx.y * 64, n0 = blockIdx.x * 64;
    const int t = threadIdx.x;
    #pragma unroll
    for (int it = 0; it < 4; ++it) {
        const int f = it * 256 + t;
        const int r = f >> 4, c4 = (f & 15) * 4;
        const float4 w4 = *(const float4*)&W[(size_t)(k0 + r) * EMB + n0 + c4];
        Ws[r][c4 + 0] = w4.x; Ws[r][c4 + 1] = w4.y;
        Ws[r][c4 + 2] = w4.z; Ws[r][c4 + 3] = w4.w;
    }
    __syncthreads();
    #pragma unroll
    for (int it = 0; it < 2; ++it) {
        const int f = it * 256 + t;
        const int n = f >> 3, k8 = (f & 7) * 8;
        short8 ph, pm, pl;
        #pragma unroll
        for (int j = 0; j < 8; ++j) {
            unsigned short h, m, l;
            split3(Ws[k8 + j][n], h, m, l);
            ph[j] = (short)h; pm[j] = (short)m; pl[j] = (short)l;
        }
        const size_t o = obase + (size_t)(n0 + n) * EMB + k0 + k8;
        *(short8*)&th[o] = ph;
        *(short8*)&tm[o] = pm;
        *(short8*)&tl[o] = pl;
    }
}

// ---------------------------------------------------------------------------
// K1c: QKV GEMM via bf16x6 MFMA + f32 LIF epilogue, bf16 out.
// 1-D grid (1536 blocks) with an XCD-locality swizzle: xcd = L&7 owns a
// contiguous 512-row slice of x across all col-tiles and all z, so the
// per-XCD per-z working set (1.5 MB x-slice + 1.5 MB W_z splits) fits the
// 4 MB XCD L2. (R8: default mapping made every XCD stream all 16.5 MB from
// HBM — FETCH 131 MB, latency-bound at MfmaUtil 10%.)
// ---------------------------------------------------------------------------
__global__ __launch_bounds__(256) void qkv_mfma_lif_kernel(
    const unsigned short* __restrict__ xh, const unsigned short* __restrict__ xm,
    const unsigned short* __restrict__ xl,
    const unsigned short* __restrict__ wth, const unsigned short* __restrict__ wtm,
    const unsigned short* __restrict__ wtl,   // stacked: z*EMB*EMB
    const float* __restrict__ aq, const float* __restrict__ bq,
    const float* __restrict__ akp, const float* __restrict__ bkp,
    const float* __restrict__ av, const float* __restrict__ bv,
    const int* __restrict__ T_i,
    unsigned short* __restrict__ q_sum, unsigned short* __restrict__ k_sum,
    unsigned short* __restrict__ v_mean)
{
    // swizzle: L = xcd + 8*(r8 + 8*c8 + 64*z)
    const int L   = blockIdx.x;
    const int xcd = L & 7;
    const int t5  = L >> 3;          // 0..191
    const int z   = t5 >> 6;         // 0..2
    const int r8  = t5 & 7;          // row-tile within this xcd's slice
    const int c8  = (t5 >> 3) & 7;   // col-tile 0..7
    const int row0 = (xcd * 8 + r8) * 64;
    const int col0 = c8 * 64;

    unsigned short* __restrict__ out = (z == 0) ? q_sum : (z == 1) ? k_sum : v_mean;
    const float alpha = ((z == 0) ? aq : (z == 1) ? akp : av)[0];
    const float beta  = ((z == 0) ? bq : (z == 1) ? bkp : bv)[0];
    const size_t wbase = (size_t)z * EMB * EMB;

    const int tid  = threadIdx.x;
    const int lane = tid & 63, wave = tid >> 6;
    const int qd = lane >> 4, c = lane & 15;
    const int wm = (wave & 1) * 32, wn = (wave >> 1) * 32;

    float4v acc[2][2];
    #pragma unroll
    for (int i = 0; i < 2; ++i)
        #pragma unroll
        for (int j = 0; j < 2; ++j)
            acc[i][j] = (float4v){0.f, 0.f, 0.f, 0.f};

    for (int k0 = 0; k0 < EMB; k0 += 32) {
        short8 ah[2], am[2], al[2], bh[2], bm[2], bl[2];
        #pragma unroll
        for (int i = 0; i < 2; ++i) {
            const size_t ao = (size_t)(row0 + wm + i * 16 + c) * EMB + k0 + qd * 8;
            ah[i] = *(const short8*)&xh[ao];
            am[i] = *(const short8*)&xm[ao];
            al[i] = *(const short8*)&xl[ao];
        }
        #pragma unroll
        for (int j = 0; j < 2; ++j) {
            const size_t bo = wbase + (size_t)(col0 + wn + j * 16 + c) * EMB + k0 + qd * 8;
            bh[j] = *(const short8*)&wth[bo];
            bm[j] = *(const short8*)&wtm[bo];
            bl[j] = *(const short8*)&wtl[bo];
        }
        #pragma unroll
        for (int i = 0; i < 2; ++i)
            #pragma unroll
            for (int j = 0; j < 2; ++j) {
                float4v a = acc[i][j];
                a = __builtin_amdgcn_mfma_f32_16x16x32_bf16(al[i], bh[j], a, 0, 0, 0);
                a = __builtin_amdgcn_mfma_f32_16x16x32_bf16(am[i], bm[j], a, 0, 0, 0);
                a = __builtin_amdgcn_mfma_f32_16x16x32_bf16(ah[i], bl[j], a, 0, 0, 0);
                a = __builtin_amdgcn_mfma_f32_16x16x32_bf16(am[i], bh[j], a, 0, 0, 0);
                a = __builtin_amdgcn_mfma_f32_16x16x32_bf16(ah[i], bm[j], a, 0, 0, 0);
                a = __builtin_amdgcn_mfma_f32_16x16x32_bf16(ah[i], bh[j], a, 0, 0, 0);
                acc[i][j] = a;
            }
    }

    // LIF epilogue: f32, np-exact op order
    #pragma unroll
    for (int i = 0; i < 2; ++i)
        #pragma unroll
        for (int r = 0; r < 4; ++r) {
            const int gm = row0 + wm + i * 16 + qd * 4 + r;
            const int T = T_i[gm];
            #pragma unroll
            for (int j = 0; j < 2; ++j) {
                const float xv = acc[i][j][r];
                float cur = 0.f, vm = 0.f, spikes = 0.f;
                for (int t = 0; t < T; ++t) {
                    cur = __fadd_rn(__fmul_rn(alpha, cur), xv);
                    vm  = __fadd_rn(__fmul_rn(beta, vm), cur);
                    if (vm >= 1.0f) { spikes += 1.0f; vm = 0.f; }
                }
                if (z == 2) spikes = spikes / 20.0f;
                out[(size_t)gm * EMB + col0 + wn + j * 16 + c] = f2bf(spikes);
            }
        }
}

// ---------------------------------------------------------------------------
// K2: fused flash-style MFMA attention; epilogue emits bf16. (unchanged)
// ---------------------------------------------------------------------------
__global__ __launch_bounds__(256) void attn_mfma_kernel(
    const unsigned short* __restrict__ q, const unsigned short* __restrict__ k,
    const unsigned short* __restrict__ v, unsigned short* __restrict__ attn_bf)
{
    __shared__ __align__(16) short Ks[64 * LDP];
    __shared__ __align__(16) short Pt[64 * LDP];
    __shared__ __align__(16) short Vt[64 * LDP];

    const int b = blockIdx.z, h = blockIdx.y;
    const int i0 = blockIdx.x * 64;
    const int tid  = threadIdx.x;
    const int wave = tid >> 6, lane = tid & 63;
    const int quad = lane >> 4, c = lane & 15;

    const unsigned short* Qb = q + ((size_t)b * SEQ + i0) * EMB + h * 64;
    const unsigned short* Kb = k + (size_t)b * SEQ * EMB + h * 64;
    const unsigned short* Vb = v + (size_t)b * SEQ * EMB + h * 64;

    short8 qf[2];
    {
        const int qrow = wave * 16 + c;
        #pragma unroll
        for (int ks = 0; ks < 2; ++ks) {
            short8 raw = *(const short8*)(Qb + (size_t)qrow * EMB + ks * 32 + quad * 8);
            short8 sc8;
            #pragma unroll
            for (int j = 0; j < 8; ++j)
                sc8[j] = (short)f2bf(bf2f((unsigned short)raw[j]) * 0.125f);
            qf[ks] = sc8;
        }
    }

    float m_r[4], l_r[4];
    float4v o[4];
    #pragma unroll
    for (int r = 0; r < 4; ++r) { m_r[r] = -1e30f; l_r[r] = 0.f; }
    #pragma unroll
    for (int nb = 0; nb < 4; ++nb)
        #pragma unroll
        for (int r = 0; r < 4; ++r) o[nb][r] = 0.f;

    for (int jt = 0; jt < SEQ / 64; ++jt) {
        #pragma unroll
        for (int it = 0; it < 2; ++it) {
            const int idx = it * 256 + tid;
            const int row = idx >> 3, ch = idx & 7;
            short8 val = *(const short8*)(Kb + (size_t)(jt * 64 + row) * EMB + ch * 8);
            *(short8*)&Ks[row * LDP + ch * 8] = val;
        }
        __syncthreads();

        float sc[4][4];
        #pragma unroll
        for (int nb = 0; nb < 4; ++nb) {
            float4v acc = {0.f, 0.f, 0.f, 0.f};
            #pragma unroll
            for (int ks = 0; ks < 2; ++ks) {
                short8 bfrag = *(const short8*)&Ks[(nb * 16 + c) * LDP + ks * 32 + quad * 8];
                acc = __builtin_amdgcn_mfma_f32_16x16x32_bf16(qf[ks], bfrag, acc, 0, 0, 0);
            }
            #pragma unroll
            for (int r = 0; r < 4; ++r) sc[nb][r] = acc[r];
        }

        float mnew[4], alpha[4];
        #pragma unroll
        for (int r = 0; r < 4; ++r) {
            float mx = fmaxf(fmaxf(sc[0][r], sc[1][r]), fmaxf(sc[2][r], sc[3][r]));
            #pragma unroll
            for (int off = 8; off >= 1; off >>= 1) mx = fmaxf(mx, __shfl_xor(mx, off));
            mnew[r]  = fmaxf(m_r[r], mx);
            alpha[r] = __expf(m_r[r] - mnew[r]);
            m_r[r]   = mnew[r];
        }
        float psum[4] = {0.f, 0.f, 0.f, 0.f};
        #pragma unroll
        for (int nb = 0; nb < 4; ++nb)
            #pragma unroll
            for (int r = 0; r < 4; ++r) {
                float p = __expf(sc[nb][r] - mnew[r]);
                psum[r] += p;
                Pt[(wave * 16 + quad * 4 + r) * LDP + nb * 16 + c] = (short)f2bf(p);
            }
        #pragma unroll
        for (int r = 0; r < 4; ++r) {
            float s = psum[r];
            #pragma unroll
            for (int off = 8; off >= 1; off >>= 1) s += __shfl_xor(s, off);
            l_r[r] = l_r[r] * alpha[r] + s;
            #pragma unroll
            for (int nb = 0; nb < 4; ++nb) o[nb][r] *= alpha[r];
        }

        {
            const int m = tid & 7, rp = tid >> 3;
            const int r = rp * 2;
            short8 v0 = *(const short8*)(Vb + (size_t)(jt * 64 + r) * EMB + m * 8);
            short8 v1 = *(const short8*)(Vb + (size_t)(jt * 64 + r + 1) * EMB + m * 8);
            const int rch = r >> 3, rlow = r & 7;
            #pragma unroll
            for (int i = 0; i < 8; ++i) {
                const int d = m * 8 + i;
                const int col = ((rch ^ m) << 3) + rlow;
                *(int*)&Vt[d * LDP + col] =
                    (int)((unsigned)(unsigned short)v0[i] |
                          ((unsigned)(unsigned short)v1[i] << 16));
            }
        }
        __syncthreads();

        short8 pf[2];
        #pragma unroll
        for (int ks = 0; ks < 2; ++ks)
            pf[ks] = *(const short8*)&Pt[(wave * 16 + c) * LDP + ks * 32 + quad * 8];
        #pragma unroll
        for (int nb = 0; nb < 4; ++nb) {
            float4v acc = o[nb];
            #pragma unroll
            for (int ks = 0; ks < 2; ++ks) {
                const int d = nb * 16 + c;
                const int kch = ks * 4 + quad;
                const int col = ((kch ^ (d >> 3)) << 3);
                short8 vfrag = *(const short8*)&Vt[d * LDP + col];
                acc = __builtin_amdgcn_mfma_f32_16x16x32_bf16(pf[ks], vfrag, acc, 0, 0, 0);
            }
            o[nb] = acc;
        }
    }

    #pragma unroll
    for (int r = 0; r < 4; ++r) {
        const float inv = 1.0f / l_r[r];
        const int row = i0 + wave * 16 + quad * 4 + r;
        #pragma unroll
        for (int nb = 0; nb < 4; ++nb)
            attn_bf[((size_t)b * SEQ + row) * EMB + h * 64 + nb * 16 + c] =
                f2bf(o[nb][r] * inv);
    }
}

// ---------------------------------------------------------------------------
// K3a: Wo^T bf16 prep (64x64 LDS transpose tiles). (unchanged)
// ---------------------------------------------------------------------------
__global__ __launch_bounds__(256) void wot_prep(
    const float* __restrict__ Wo, unsigned short* __restrict__ BT)
{
    __shared__ unsigned short Ws[64][72];
    const int k0 = blockIdx.y * 64, n0 = blockIdx.x * 64;
    const int t = threadIdx.x;
    #pragma unroll
    for (int it = 0; it < 4; ++it) {
        const int idx = it * 256 + t;
        const int r = idx >> 4, c4 = (idx & 15) * 4;
        const float4 w4 = *(const float4*)&Wo[(size_t)(k0 + r) * EMB + n0 + c4];
        Ws[r][c4 + 0] = f2bf(w4.x); Ws[r][c4 + 1] = f2bf(w4.y);
        Ws[r][c4 + 2] = f2bf(w4.z); Ws[r][c4 + 3] = f2bf(w4.w);
    }
    __syncthreads();
    #pragma unroll
    for (int it = 0; it < 2; ++it) {
        const int idx = it * 256 + t;
        const int n = idx >> 3, k8 = (idx & 7) * 8;
        short8 pack;
        #pragma unroll
        for (int j = 0; j < 8; ++j) pack[j] = (short)Ws[k8 + j][n];
        *(short8*)&BT[(size_t)(n0 + n) * EMB + k0 + k8] = pack;
    }
}

// ---------------------------------------------------------------------------
// K3b: out = attn_bf @ Wo + bo via bf16 MFMA. (unchanged)
// ---------------------------------------------------------------------------
__global__ __launch_bounds__(256) void out_gemm_kernel(
    const unsigned short* __restrict__ A,   // [4096][512] bf16
    const unsigned short* __restrict__ BT,  // [512][512] bf16, [n][k]
    const float* __restrict__ bias, float* __restrict__ out)
{
    const int tid  = threadIdx.x;
    const int lane = tid & 63, wave = tid >> 6;
    const int qd = lane >> 4, c = lane & 15;
    const int wm = (wave & 1) * 32, wn = (wave >> 1) * 32;
    const int row0 = blockIdx.y * 64, col0 = blockIdx.x * 64;

    float4v acc[2][2];
    #pragma unroll
    for (int i = 0; i < 2; ++i)
        #pragma unroll
        for (int j = 0; j < 2; ++j)
            acc[i][j] = (float4v){0.f, 0.f, 0.f, 0.f};

    for (int k0 = 0; k0 < EMB; k0 += 32) {
        short8 af[2], bf[2];
        #pragma unroll
        for (int i = 0; i < 2; ++i)
            af[i] = *(const short8*)&A[(size_t)(row0 + wm + i * 16 + c) * EMB + k0 + qd * 8];
        #pragma unroll
        for (int j = 0; j < 2; ++j)
            bf[j] = *(const short8*)&BT[(size_t)(col0 + wn + j * 16 + c) * EMB + k0 + qd * 8];
        #pragma unroll
        for (int i = 0; i < 2; ++i)
            #pragma unroll
            for (int j = 0; j < 2; ++j)
                acc[i][j] = __builtin_amdgcn_mfma_f32_16x16x32_bf16(af[i], bf[j], acc[i][j], 0, 0, 0);
    }

    #pragma unroll
    for (int i = 0; i < 2; ++i)
        #pragma unroll
        for (int r = 0; r < 4; ++r) {
            const int gm = row0 + wm + i * 16 + qd * 4 + r;
            #pragma unroll
            for (int j = 0; j < 2; ++j) {
                const int gn = col0 + wn + j * 16 + c;
                out[(size_t)gm * EMB + gn] = acc[i][j][r] + bias[gn];
            }
        }
}

// ---------------------------------------------------------------------------
extern "C" void kernel_launch(void* const* d_in, const int* in_sizes, int n_in,
                              void* d_out, int out_size, void* d_ws, size_t ws_size,
                              hipStream_t stream)
{
    const float* x   = (const float*)d_in[0];
    const float* Wq  = (const float*)d_in[1];
    const float* Wk  = (const float*)d_in[2];
    const float* Wv  = (const float*)d_in[3];
    const float* Wo  = (const float*)d_in[4];
    const float* bo  = (const float*)d_in[5];
    const float* gW1 = (const float*)d_in[6];
    const float* gb1 = (const float*)d_in[7];
    const float* gg  = (const float*)d_in[8];
    const float* gbe = (const float*)d_in[9];
    const float* gW2 = (const float*)d_in[10];
    const float* gb2 = (const float*)d_in[11];
    const float* gW3 = (const float*)d_in[12];
    const float* gb3 = (const float*)d_in[13];
    const float* cW1 = (const float*)d_in[14];
    const float* cb1 = (const float*)d_in[15];
    const float* cg  = (const float*)d_in[16];
    const float* cbe = (const float*)d_in[17];
    const float* cW2 = (const float*)d_in[18];
    const float* cb2 = (const float*)d_in[19];
    const float* cW3 = (const float*)d_in[20];
    const float* cb3 = (const float*)d_in[21];
    const float* aq  = (const float*)d_in[22];
    const float* bq  = (const float*)d_in[23];
    const float* ak  = (const float*)d_in[24];
    const float* bk  = (const float*)d_in[25];
    const float* av  = (const float*)d_in[26];
    const float* bv  = (const float*)d_in[27];

    char* ws = (char*)d_ws;
    int* Tp = (int*)ws;                                   // 16 KB
    const size_t SZ = (size_t)NROWS * EMB * 2;            // 4 MB (bf16 4096x512)
    const size_t WZ = (size_t)EMB * EMB * 2;              // 512 KB
    unsigned short* q_sum   = (unsigned short*)(ws + 16384);
    unsigned short* k_sum   = (unsigned short*)(ws + 16384 + SZ);
    unsigned short* v_mean  = (unsigned short*)(ws + 16384 + 2 * SZ);
    unsigned short* attn_bf = (unsigned short*)(ws + 16384 + 3 * SZ);
    unsigned short* WoT     = (unsigned short*)(ws + 16384 + 4 * SZ);
    unsigned short* xh      = (unsigned short*)(ws + 16384 + 4 * SZ + WZ);
    unsigned short* xm      = (unsigned short*)(ws + 16384 + 5 * SZ + WZ);
    unsigned short* xl      = (unsigned short*)(ws + 16384 + 6 * SZ + WZ);
    unsigned short* WTh     = (unsigned short*)(ws + 16384 + 7 * SZ + WZ);       // 3 stacked
    unsigned short* WTm     = (unsigned short*)(ws + 16384 + 7 * SZ + 4 * WZ);
    unsigned short* WTl     = (unsigned short*)(ws + 16384 + 7 * SZ + 7 * WZ);
    float* out = (float*)d_out;

    gates_kernel<<<dim3(NROWS / GROWS), dim3(256), 0, stream>>>(
        x, gW1, gb1, gg, gbe, gW2, gb2, gW3, gb3,
        cW1, cb1, cg, cbe, cW2, cb2, cW3, cb3, Tp);

    split_x_kernel<<<dim3(NROWS * EMB / 1024), dim3(256), 0, stream>>>(x, xh, xm, xl);

    split_wt_kernel<<<dim3(EMB / 64, EMB / 64, 3), dim3(256), 0, stream>>>(
        Wq, Wk, Wv, WTh, WTm, WTl);

    qkv_mfma_lif_kernel<<<dim3(1536), dim3(256), 0, stream>>>(
        xh, xm, xl, WTh, WTm, WTl, aq, bq, ak, bk, av, bv, Tp,
        q_sum, k_sum, v_mean);

    wot_prep<<<dim3(EMB / 64, EMB / 64), dim3(256), 0, stream>>>(Wo, WoT);

    attn_mfma_kernel<<<dim3(SEQ / 64, 8, 4), dim3(256), 0, stream>>>(
        q_sum, k_sum, v_mean, attn_bf);

    out_gemm_kernel<<<dim3(EMB / 64, NROWS / 64), dim3(256), 0, stream>>>(
        attn_bf, WoT, bo, out);
}

// Round 10
// 360.284 us; speedup vs baseline: 1.0196x; 1.0196x over previous
//
#include <hip/hip_runtime.h>
#include <math.h>

// Problem constants (B=4, S=1024, E=512, H=8, D=64, T_MAX=20)
#define SEQ   1024
#define EMB   512
#define NROWS 4096   // B*S
#define LDP   72     // attn LDS row stride (bf16 elems)
#define GROWS 8      // gates rows per block

typedef __attribute__((ext_vector_type(8))) short short8;    // bf16 x8 MFMA frag
typedef __attribute__((ext_vector_type(4))) float float4v;   // f32 x4 MFMA acc

__device__ __forceinline__ float bf2f(unsigned short s) {
    union { float f; unsigned u; } x; x.u = ((unsigned)s) << 16; return x.f;
}
__device__ __forceinline__ unsigned short f2bf(float f) {
    union { float f; unsigned u; } x; x.f = f;
    unsigned r = x.u + 0x7fffu + ((x.u >> 16) & 1u);   // round-to-nearest-even
    return (unsigned short)(r >> 16);
}
// 3-way bf16 split: v ~= h + m + l, residual <= 2^-27 |v|
__device__ __forceinline__ void split3(float v, unsigned short& h, unsigned short& m, unsigned short& l) {
    h = f2bf(v);
    float r1 = v - bf2f(h);
    m = f2bf(r1);
    float r2 = r1 - bf2f(m);
    l = f2bf(r2);
}

// ---------------------------------------------------------------------------
// K0: gate + complexity MLPs -> T_i[4096]. 8 rows per block. All-f32.
// ---------------------------------------------------------------------------
template<int H1, int H2>
__device__ __forceinline__ float gate_mlp_block(
    const float xs[GROWS][EMB], float h1[GROWS][128], float h2[GROWS][64],
    float* mu_s, float* var_s,
    const float* __restrict__ W1, const float* __restrict__ b1,
    const float* __restrict__ gam, const float* __restrict__ bet,
    const float* __restrict__ W2, const float* __restrict__ b2,
    const float* __restrict__ W3, const float* __restrict__ b3,
    int tid, int myrow)
{
    constexpr int RN1 = GROWS * H1 / 256;
    constexpr int RN2 = GROWS * H2 / 256;

    {   // h1 = x @ W1 + b1
        const int col = tid % H1;
        const int rb  = (tid / H1) * RN1;
        float acc[RN1];
        #pragma unroll
        for (int r = 0; r < RN1; ++r) acc[r] = b1[col];
        for (int k = 0; k < EMB; ++k) {
            const float w = W1[k * H1 + col];
            #pragma unroll
            for (int r = 0; r < RN1; ++r) acc[r] += w * xs[rb + r][k];
        }
        #pragma unroll
        for (int r = 0; r < RN1; ++r) h1[rb + r][col] = acc[r];
    }
    __syncthreads();

    {   // mean
        const int r = tid >> 5, l = tid & 31;
        float s = 0.f;
        for (int c = l; c < H1; c += 32) s += h1[r][c];
        #pragma unroll
        for (int off = 16; off >= 1; off >>= 1) s += __shfl_xor(s, off);
        if (l == 0) mu_s[r] = s / (float)H1;
    }
    __syncthreads();
    {   // var
        const int r = tid >> 5, l = tid & 31;
        const float mu = mu_s[r];
        float s = 0.f;
        for (int c = l; c < H1; c += 32) { const float d = h1[r][c] - mu; s += d * d; }
        #pragma unroll
        for (int off = 16; off >= 1; off >>= 1) s += __shfl_xor(s, off);
        if (l == 0) var_s[r] = s / (float)H1;
    }
    __syncthreads();
    for (int idx = tid; idx < GROWS * H1; idx += 256) {
        const int r = idx / H1, cc = idx % H1;
        float hn = (h1[r][cc] - mu_s[r]) / sqrtf(var_s[r] + 1e-5f) * gam[cc] + bet[cc];
        h1[r][cc] = hn > 0.f ? hn : 0.f;
    }
    __syncthreads();

    {   // h2 = relu(h1 @ W2 + b2)
        const int col = tid % H2;
        const int rb  = (tid / H2) * RN2;
        float acc[RN2];
        #pragma unroll
        for (int r = 0; r < RN2; ++r) acc[r] = b2[col];
        for (int k = 0; k < H1; ++k) {
            const float w = W2[k * H2 + col];
            #pragma unroll
            for (int r = 0; r < RN2; ++r) acc[r] += w * h1[rb + r][k];
        }
        #pragma unroll
        for (int r = 0; r < RN2; ++r) h2[rb + r][col] = acc[r] > 0.f ? acc[r] : 0.f;
    }
    __syncthreads();

    {   // scalar = h2 @ W3
        const int r = tid >> 5, l = tid & 31;
        float s = 0.f;
        for (int c = l; c < H2; c += 32) s += h2[r][c] * W3[c];
        #pragma unroll
        for (int off = 16; off >= 1; off >>= 1) s += __shfl_xor(s, off);
        if (l == 0) mu_s[r] = s;
    }
    __syncthreads();
    float ret = 0.f;
    if (myrow >= 0) {
        const float z = mu_s[myrow] + b3[0];
        ret = 1.0f / (1.0f + expf(-z));
    }
    __syncthreads();
    return ret;
}

__global__ __launch_bounds__(256) void gates_kernel(
    const float* __restrict__ x,
    const float* __restrict__ gW1, const float* __restrict__ gb1,
    const float* __restrict__ gg,  const float* __restrict__ gbe,
    const float* __restrict__ gW2, const float* __restrict__ gb2,
    const float* __restrict__ gW3, const float* __restrict__ gb3,
    const float* __restrict__ cW1, const float* __restrict__ cb1,
    const float* __restrict__ cg,  const float* __restrict__ cbe,
    const float* __restrict__ cW2, const float* __restrict__ cb2,
    const float* __restrict__ cW3, const float* __restrict__ cb3,
    int* __restrict__ T_i)
{
    __shared__ float xs[GROWS][EMB];
    __shared__ float h1[GROWS][128];
    __shared__ float h2[GROWS][64];
    __shared__ float mu_s[GROWS], var_s[GROWS];

    const int row0 = blockIdx.x * GROWS;
    const int tid = threadIdx.x;

    for (int idx = tid; idx < GROWS * EMB; idx += 256) {
        const int r = idx >> 9, cc = idx & 511;
        xs[r][cc] = x[(size_t)(row0 + r) * EMB + cc];
    }
    __syncthreads();

    const int myrow = (tid < GROWS) ? tid : -1;
    const float g0 = gate_mlp_block<128, 64>(xs, h1, h2, mu_s, var_s,
                                             gW1, gb1, gg, gbe, gW2, gb2, gW3, gb3, tid, myrow);
    const float c0 = gate_mlp_block<64, 32>(xs, h1, h2, mu_s, var_s,
                                            cW1, cb1, cg, cbe, cW2, cb2, cW3, cb3, tid, myrow);

    if (tid < GROWS) {
        const int row = row0 + tid;
        const int s = row & (SEQ - 1);
        const float step = (1.2f - 0.8f) / (float)(SEQ - 1);
        const float pos  = (float)s * step + 0.8f;
        const float score = ((1.0f - 0.3f) * g0 + 0.3f * c0) * pos;
        float t = ceilf(score * 20.0f);
        t = t < 1.f ? 1.f : (t > 20.f ? 20.f : t);
        T_i[row] = (int)t;
    }
}

// ---------------------------------------------------------------------------
// K1a: split x into 3 bf16 arrays (elementwise).
// ---------------------------------------------------------------------------
__global__ __launch_bounds__(256) void split_x_kernel(
    const float* __restrict__ src,
    unsigned short* __restrict__ xh, unsigned short* __restrict__ xm,
    unsigned short* __restrict__ xl)
{
    const int i4 = (blockIdx.x * 256 + threadIdx.x) * 4;
    const float4 v = *(const float4*)&src[i4];
    ushort4 h4, m4, l4;
    split3(v.x, h4.x, m4.x, l4.x);
    split3(v.y, h4.y, m4.y, l4.y);
    split3(v.z, h4.z, m4.z, l4.z);
    split3(v.w, h4.w, m4.w, l4.w);
    *(ushort4*)&xh[i4] = h4;
    *(ushort4*)&xm[i4] = m4;
    *(ushort4*)&xl[i4] = l4;
}

// ---------------------------------------------------------------------------
// K1b: transpose + 3-way split Wq/Wk/Wv (z = blockIdx.z selects the weight).
// ---------------------------------------------------------------------------
__global__ __launch_bounds__(256) void split_wt_kernel(
    const float* __restrict__ Wq, const float* __restrict__ Wk,
    const float* __restrict__ Wv,
    unsigned short* __restrict__ th, unsigned short* __restrict__ tm,
    unsigned short* __restrict__ tl)
{
    __shared__ float Ws[64][65];
    const int z = blockIdx.z;
    const float* __restrict__ W = (z == 0) ? Wq : (z == 1) ? Wk : Wv;
    const size_t obase = (size_t)z * EMB * EMB;
    const int k0 = blockIdx.y * 64, n0 = blockIdx.x * 64;
    const int t = threadIdx.x;
    #pragma unroll
    for (int it = 0; it < 4; ++it) {
        const int f = it * 256 + t;
        const int r = f >> 4, c4 = (f & 15) * 4;
        const float4 w4 = *(const float4*)&W[(size_t)(k0 + r) * EMB + n0 + c4];
        Ws[r][c4 + 0] = w4.x; Ws[r][c4 + 1] = w4.y;
        Ws[r][c4 + 2] = w4.z; Ws[r][c4 + 3] = w4.w;
    }
    __syncthreads();
    #pragma unroll
    for (int it = 0; it < 2; ++it) {
        const int f = it * 256 + t;
        const int n = f >> 3, k8 = (f & 7) * 8;
        short8 ph, pm, pl;
        #pragma unroll
        for (int j = 0; j < 8; ++j) {
            unsigned short h, m, l;
            split3(Ws[k8 + j][n], h, m, l);
            ph[j] = (short)h; pm[j] = (short)m; pl[j] = (short)l;
        }
        const size_t o = obase + (size_t)(n0 + n) * EMB + k0 + k8;
        *(short8*)&th[o] = ph;
        *(short8*)&tm[o] = pm;
        *(short8*)&tl[o] = pl;
    }
}

// ---------------------------------------------------------------------------
// K1c: QKV GEMM via bf16x6 MFMA + f32 LIF epilogue, bf16 out.
// XCD-locality swizzle (R9: FETCH 131->28 MB) + register double-buffered
// prefetch (this round): loads for k+1 issued before MFMAs of k, so the
// compiler emits partial vmcnt waits instead of draining to zero — the
// R9 bottleneck was serial load->use latency (MfmaUtil 10%, all pipes idle).
// ---------------------------------------------------------------------------
__global__ __launch_bounds__(256) void qkv_mfma_lif_kernel(
    const unsigned short* __restrict__ xh, const unsigned short* __restrict__ xm,
    const unsigned short* __restrict__ xl,
    const unsigned short* __restrict__ wth, const unsigned short* __restrict__ wtm,
    const unsigned short* __restrict__ wtl,   // stacked: z*EMB*EMB
    const float* __restrict__ aq, const float* __restrict__ bq,
    const float* __restrict__ akp, const float* __restrict__ bkp,
    const float* __restrict__ av, const float* __restrict__ bv,
    const int* __restrict__ T_i,
    unsigned short* __restrict__ q_sum, unsigned short* __restrict__ k_sum,
    unsigned short* __restrict__ v_mean)
{
    // swizzle: L = xcd + 8*(r8 + 8*c8 + 64*z)
    const int L   = blockIdx.x;
    const int xcd = L & 7;
    const int t5  = L >> 3;          // 0..191
    const int z   = t5 >> 6;         // 0..2
    const int r8  = t5 & 7;          // row-tile within this xcd's slice
    const int c8  = (t5 >> 3) & 7;   // col-tile 0..7
    const int row0 = (xcd * 8 + r8) * 64;
    const int col0 = c8 * 64;

    unsigned short* __restrict__ out = (z == 0) ? q_sum : (z == 1) ? k_sum : v_mean;
    const float alpha = ((z == 0) ? aq : (z == 1) ? akp : av)[0];
    const float beta  = ((z == 0) ? bq : (z == 1) ? bkp : bv)[0];
    const size_t wbase = (size_t)z * EMB * EMB;

    const int tid  = threadIdx.x;
    const int lane = tid & 63, wave = tid >> 6;
    const int qd = lane >> 4, c = lane & 15;
    const int wm = (wave & 1) * 32, wn = (wave >> 1) * 32;

    float4v acc[2][2];
    #pragma unroll
    for (int i = 0; i < 2; ++i)
        #pragma unroll
        for (int j = 0; j < 2; ++j)
            acc[i][j] = (float4v){0.f, 0.f, 0.f, 0.f};

    // fragment base offsets (k0 added per iteration)
    const size_t ao0 = (size_t)(row0 + wm + c) * EMB + qd * 8;          // i=0
    const size_t ao1 = ao0 + (size_t)16 * EMB;                           // i=1
    const size_t bo0 = wbase + (size_t)(col0 + wn + c) * EMB + qd * 8;   // j=0
    const size_t bo1 = bo0 + (size_t)16 * EMB;                           // j=1

    short8 Ah[2][2], Am[2][2], Al[2][2], Bh[2][2], Bm[2][2], Bl[2][2];  // [buf][i/j]

    // prologue: load k0 = 0 into buffer 0
    Ah[0][0] = *(const short8*)&xh[ao0];  Ah[0][1] = *(const short8*)&xh[ao1];
    Am[0][0] = *(const short8*)&xm[ao0];  Am[0][1] = *(const short8*)&xm[ao1];
    Al[0][0] = *(const short8*)&xl[ao0];  Al[0][1] = *(const short8*)&xl[ao1];
    Bh[0][0] = *(const short8*)&wth[bo0]; Bh[0][1] = *(const short8*)&wth[bo1];
    Bm[0][0] = *(const short8*)&wtm[bo0]; Bm[0][1] = *(const short8*)&wtm[bo1];
    Bl[0][0] = *(const short8*)&wtl[bo0]; Bl[0][1] = *(const short8*)&wtl[bo1];

    #pragma unroll
    for (int it = 0; it < EMB / 32; ++it) {
        const int cur = it & 1, nxt = cur ^ 1;
        if (it + 1 < EMB / 32) {
            const int k1 = (it + 1) * 32;
            Ah[nxt][0] = *(const short8*)&xh[ao0 + k1];  Ah[nxt][1] = *(const short8*)&xh[ao1 + k1];
            Am[nxt][0] = *(const short8*)&xm[ao0 + k1];  Am[nxt][1] = *(const short8*)&xm[ao1 + k1];
            Al[nxt][0] = *(const short8*)&xl[ao0 + k1];  Al[nxt][1] = *(const short8*)&xl[ao1 + k1];
            Bh[nxt][0] = *(const short8*)&wth[bo0 + k1]; Bh[nxt][1] = *(const short8*)&wth[bo1 + k1];
            Bm[nxt][0] = *(const short8*)&wtm[bo0 + k1]; Bm[nxt][1] = *(const short8*)&wtm[bo1 + k1];
            Bl[nxt][0] = *(const short8*)&wtl[bo0 + k1]; Bl[nxt][1] = *(const short8*)&wtl[bo1 + k1];
        }
        #pragma unroll
        for (int i = 0; i < 2; ++i)
            #pragma unroll
            for (int j = 0; j < 2; ++j) {
                float4v a = acc[i][j];
                a = __builtin_amdgcn_mfma_f32_16x16x32_bf16(Al[cur][i], Bh[cur][j], a, 0, 0, 0);
                a = __builtin_amdgcn_mfma_f32_16x16x32_bf16(Am[cur][i], Bm[cur][j], a, 0, 0, 0);
                a = __builtin_amdgcn_mfma_f32_16x16x32_bf16(Ah[cur][i], Bl[cur][j], a, 0, 0, 0);
                a = __builtin_amdgcn_mfma_f32_16x16x32_bf16(Am[cur][i], Bh[cur][j], a, 0, 0, 0);
                a = __builtin_amdgcn_mfma_f32_16x16x32_bf16(Ah[cur][i], Bm[cur][j], a, 0, 0, 0);
                a = __builtin_amdgcn_mfma_f32_16x16x32_bf16(Ah[cur][i], Bh[cur][j], a, 0, 0, 0);
                acc[i][j] = a;
            }
    }

    // LIF epilogue: f32, np-exact op order
    #pragma unroll
    for (int i = 0; i < 2; ++i)
        #pragma unroll
        for (int r = 0; r < 4; ++r) {
            const int gm = row0 + wm + i * 16 + qd * 4 + r;
            const int T = T_i[gm];
            #pragma unroll
            for (int j = 0; j < 2; ++j) {
                const float xv = acc[i][j][r];
                float cur = 0.f, vm = 0.f, spikes = 0.f;
                for (int t = 0; t < T; ++t) {
                    cur = __fadd_rn(__fmul_rn(alpha, cur), xv);
                    vm  = __fadd_rn(__fmul_rn(beta, vm), cur);
                    if (vm >= 1.0f) { spikes += 1.0f; vm = 0.f; }
                }
                if (z == 2) spikes = spikes / 20.0f;
                out[(size_t)gm * EMB + col0 + wn + j * 16 + c] = f2bf(spikes);
            }
        }
}

// ---------------------------------------------------------------------------
// K2: fused flash-style MFMA attention; epilogue emits bf16. (unchanged)
// ---------------------------------------------------------------------------
__global__ __launch_bounds__(256) void attn_mfma_kernel(
    const unsigned short* __restrict__ q, const unsigned short* __restrict__ k,
    const unsigned short* __restrict__ v, unsigned short* __restrict__ attn_bf)
{
    __shared__ __align__(16) short Ks[64 * LDP];
    __shared__ __align__(16) short Pt[64 * LDP];
    __shared__ __align__(16) short Vt[64 * LDP];

    const int b = blockIdx.z, h = blockIdx.y;
    const int i0 = blockIdx.x * 64;
    const int tid  = threadIdx.x;
    const int wave = tid >> 6, lane = tid & 63;
    const int quad = lane >> 4, c = lane & 15;

    const unsigned short* Qb = q + ((size_t)b * SEQ + i0) * EMB + h * 64;
    const unsigned short* Kb = k + (size_t)b * SEQ * EMB + h * 64;
    const unsigned short* Vb = v + (size_t)b * SEQ * EMB + h * 64;

    short8 qf[2];
    {
        const int qrow = wave * 16 + c;
        #pragma unroll
        for (int ks = 0; ks < 2; ++ks) {
            short8 raw = *(const short8*)(Qb + (size_t)qrow * EMB + ks * 32 + quad * 8);
            short8 sc8;
            #pragma unroll
            for (int j = 0; j < 8; ++j)
                sc8[j] = (short)f2bf(bf2f((unsigned short)raw[j]) * 0.125f);
            qf[ks] = sc8;
        }
    }

    float m_r[4], l_r[4];
    float4v o[4];
    #pragma unroll
    for (int r = 0; r < 4; ++r) { m_r[r] = -1e30f; l_r[r] = 0.f; }
    #pragma unroll
    for (int nb = 0; nb < 4; ++nb)
        #pragma unroll
        for (int r = 0; r < 4; ++r) o[nb][r] = 0.f;

    for (int jt = 0; jt < SEQ / 64; ++jt) {
        #pragma unroll
        for (int it = 0; it < 2; ++it) {
            const int idx = it * 256 + tid;
            const int row = idx >> 3, ch = idx & 7;
            short8 val = *(const short8*)(Kb + (size_t)(jt * 64 + row) * EMB + ch * 8);
            *(short8*)&Ks[row * LDP + ch * 8] = val;
        }
        __syncthreads();

        float sc[4][4];
        #pragma unroll
        for (int nb = 0; nb < 4; ++nb) {
            float4v acc = {0.f, 0.f, 0.f, 0.f};
            #pragma unroll
            for (int ks = 0; ks < 2; ++ks) {
                short8 bfrag = *(const short8*)&Ks[(nb * 16 + c) * LDP + ks * 32 + quad * 8];
                acc = __builtin_amdgcn_mfma_f32_16x16x32_bf16(qf[ks], bfrag, acc, 0, 0, 0);
            }
            #pragma unroll
            for (int r = 0; r < 4; ++r) sc[nb][r] = acc[r];
        }

        float mnew[4], alpha[4];
        #pragma unroll
        for (int r = 0; r < 4; ++r) {
            float mx = fmaxf(fmaxf(sc[0][r], sc[1][r]), fmaxf(sc[2][r], sc[3][r]));
            #pragma unroll
            for (int off = 8; off >= 1; off >>= 1) mx = fmaxf(mx, __shfl_xor(mx, off));
            mnew[r]  = fmaxf(m_r[r], mx);
            alpha[r] = __expf(m_r[r] - mnew[r]);
            m_r[r]   = mnew[r];
        }
        float psum[4] = {0.f, 0.f, 0.f, 0.f};
        #pragma unroll
        for (int nb = 0; nb < 4; ++nb)
            #pragma unroll
            for (int r = 0; r < 4; ++r) {
                float p = __expf(sc[nb][r] - mnew[r]);
                psum[r] += p;
                Pt[(wave * 16 + quad * 4 + r) * LDP + nb * 16 + c] = (short)f2bf(p);
            }
        #pragma unroll
        for (int r = 0; r < 4; ++r) {
            float s = psum[r];
            #pragma unroll
            for (int off = 8; off >= 1; off >>= 1) s += __shfl_xor(s, off);
            l_r[r] = l_r[r] * alpha[r] + s;
            #pragma unroll
            for (int nb = 0; nb < 4; ++nb) o[nb][r] *= alpha[r];
        }

        {
            const int m = tid & 7, rp = tid >> 3;
            const int r = rp * 2;
            short8 v0 = *(const short8*)(Vb + (size_t)(jt * 64 + r) * EMB + m * 8);
            short8 v1 = *(const short8*)(Vb + (size_t)(jt * 64 + r + 1) * EMB + m * 8);
            const int rch = r >> 3, rlow = r & 7;
            #pragma unroll
            for (int i = 0; i < 8; ++i) {
                const int d = m * 8 + i;
                const int col = ((rch ^ m) << 3) + rlow;
                *(int*)&Vt[d * LDP + col] =
                    (int)((unsigned)(unsigned short)v0[i] |
                          ((unsigned)(unsigned short)v1[i] << 16));
            }
        }
        __syncthreads();

        short8 pf[2];
        #pragma unroll
        for (int ks = 0; ks < 2; ++ks)
            pf[ks] = *(const short8*)&Pt[(wave * 16 + c) * LDP + ks * 32 + quad * 8];
        #pragma unroll
        for (int nb = 0; nb < 4; ++nb) {
            float4v acc = o[nb];
            #pragma unroll
            for (int ks = 0; ks < 2; ++ks) {
                const int d = nb * 16 + c;
                const int kch = ks * 4 + quad;
                const int col = ((kch ^ (d >> 3)) << 3);
                short8 vfrag = *(const short8*)&Vt[d * LDP + col];
                acc = __builtin_amdgcn_mfma_f32_16x16x32_bf16(pf[ks], vfrag, acc, 0, 0, 0);
            }
            o[nb] = acc;
        }
    }

    #pragma unroll
    for (int r = 0; r < 4; ++r) {
        const float inv = 1.0f / l_r[r];
        const int row = i0 + wave * 16 + quad * 4 + r;
        #pragma unroll
        for (int nb = 0; nb < 4; ++nb)
            attn_bf[((size_t)b * SEQ + row) * EMB + h * 64 + nb * 16 + c] =
                f2bf(o[nb][r] * inv);
    }
}

// ---------------------------------------------------------------------------
// K3a: Wo^T bf16 prep (64x64 LDS transpose tiles). (unchanged)
// ---------------------------------------------------------------------------
__global__ __launch_bounds__(256) void wot_prep(
    const float* __restrict__ Wo, unsigned short* __restrict__ BT)
{
    __shared__ unsigned short Ws[64][72];
    const int k0 = blockIdx.y * 64, n0 = blockIdx.x * 64;
    const int t = threadIdx.x;
    #pragma unroll
    for (int it = 0; it < 4; ++it) {
        const int idx = it * 256 + t;
        const int r = idx >> 4, c4 = (idx & 15) * 4;
        const float4 w4 = *(const float4*)&Wo[(size_t)(k0 + r) * EMB + n0 + c4];
        Ws[r][c4 + 0] = f2bf(w4.x); Ws[r][c4 + 1] = f2bf(w4.y);
        Ws[r][c4 + 2] = f2bf(w4.z); Ws[r][c4 + 3] = f2bf(w4.w);
    }
    __syncthreads();
    #pragma unroll
    for (int it = 0; it < 2; ++it) {
        const int idx = it * 256 + t;
        const int n = idx >> 3, k8 = (idx & 7) * 8;
        short8 pack;
        #pragma unroll
        for (int j = 0; j < 8; ++j) pack[j] = (short)Ws[k8 + j][n];
        *(short8*)&BT[(size_t)(n0 + n) * EMB + k0 + k8] = pack;
    }
}

// ---------------------------------------------------------------------------
// K3b: out = attn_bf @ Wo + bo via bf16 MFMA, register double-buffered
// prefetch (same latency fix as K1c).
// ---------------------------------------------------------------------------
__global__ __launch_bounds__(256) void out_gemm_kernel(
    const unsigned short* __restrict__ A,   // [4096][512] bf16
    const unsigned short* __restrict__ BT,  // [512][512] bf16, [n][k]
    const float* __restrict__ bias, float* __restrict__ out)
{
    const int tid  = threadIdx.x;
    const int lane = tid & 63, wave = tid >> 6;
    const int qd = lane >> 4, c = lane & 15;
    const int wm = (wave & 1) * 32, wn = (wave >> 1) * 32;
    const int row0 = blockIdx.y * 64, col0 = blockIdx.x * 64;

    float4v acc[2][2];
    #pragma unroll
    for (int i = 0; i < 2; ++i)
        #pragma unroll
        for (int j = 0; j < 2; ++j)
            acc[i][j] = (float4v){0.f, 0.f, 0.f, 0.f};

    const size_t ao0 = (size_t)(row0 + wm + c) * EMB + qd * 8;
    const size_t ao1 = ao0 + (size_t)16 * EMB;
    const size_t bo0 = (size_t)(col0 + wn + c) * EMB + qd * 8;
    const size_t bo1 = bo0 + (size_t)16 * EMB;

    short8 Af[2][2], Bf[2][2];
    Af[0][0] = *(const short8*)&A[ao0];  Af[0][1] = *(const short8*)&A[ao1];
    Bf[0][0] = *(const short8*)&BT[bo0]; Bf[0][1] = *(const short8*)&BT[bo1];

    #pragma unroll
    for (int it = 0; it < EMB / 32; ++it) {
        const int cur = it & 1, nxt = cur ^ 1;
        if (it + 1 < EMB / 32) {
            const int k1 = (it + 1) * 32;
            Af[nxt][0] = *(const short8*)&A[ao0 + k1];  Af[nxt][1] = *(const short8*)&A[ao1 + k1];
            Bf[nxt][0] = *(const short8*)&BT[bo0 + k1]; Bf[nxt][1] = *(const short8*)&BT[bo1 + k1];
        }
        #pragma unroll
        for (int i = 0; i < 2; ++i)
            #pragma unroll
            for (int j = 0; j < 2; ++j)
                acc[i][j] = __builtin_amdgcn_mfma_f32_16x16x32_bf16(Af[cur][i], Bf[cur][j], acc[i][j], 0, 0, 0);
    }

    #pragma unroll
    for (int i = 0; i < 2; ++i)
        #pragma unroll
        for (int r = 0; r < 4; ++r) {
            const int gm = row0 + wm + i * 16 + qd * 4 + r;
            #pragma unroll
            for (int j = 0; j < 2; ++j) {
                const int gn = col0 + wn + j * 16 + c;
                out[(size_t)gm * EMB + gn] = acc[i][j][r] + bias[gn];
            }
        }
}

// ---------------------------------------------------------------------------
extern "C" void kernel_launch(void* const* d_in, const int* in_sizes, int n_in,
                              void* d_out, int out_size, void* d_ws, size_t ws_size,
                              hipStream_t stream)
{
    const float* x   = (const float*)d_in[0];
    const float* Wq  = (const float*)d_in[1];
    const float* Wk  = (const float*)d_in[2];
    const float* Wv  = (const float*)d_in[3];
    const float* Wo  = (const float*)d_in[4];
    const float* bo  = (const float*)d_in[5];
    const float* gW1 = (const float*)d_in[6];
    const float* gb1 = (const float*)d_in[7];
    const float* gg  = (const float*)d_in[8];
    const float* gbe = (const float*)d_in[9];
    const float* gW2 = (const float*)d_in[10];
    const float* gb2 = (const float*)d_in[11];
    const float* gW3 = (const float*)d_in[12];
    const float* gb3 = (const float*)d_in[13];
    const float* cW1 = (const float*)d_in[14];
    const float* cb1 = (const float*)d_in[15];
    const float* cg  = (const float*)d_in[16];
    const float* cbe = (const float*)d_in[17];
    const float* cW2 = (const float*)d_in[18];
    const float* cb2 = (const float*)d_in[19];
    const float* cW3 = (const float*)d_in[20];
    const float* cb3 = (const float*)d_in[21];
    const float* aq  = (const float*)d_in[22];
    const float* bq  = (const float*)d_in[23];
    const float* ak  = (const float*)d_in[24];
    const float* bk  = (const float*)d_in[25];
    const float* av  = (const float*)d_in[26];
    const float* bv  = (const float*)d_in[27];

    char* ws = (char*)d_ws;
    int* Tp = (int*)ws;                                   // 16 KB
    const size_t SZ = (size_t)NROWS * EMB * 2;            // 4 MB (bf16 4096x512)
    const size_t WZ = (size_t)EMB * EMB * 2;              // 512 KB
    unsigned short* q_sum   = (unsigned short*)(ws + 16384);
    unsigned short* k_sum   = (unsigned short*)(ws + 16384 + SZ);
    unsigned short* v_mean  = (unsigned short*)(ws + 16384 + 2 * SZ);
    unsigned short* attn_bf = (unsigned short*)(ws + 16384 + 3 * SZ);
    unsigned short* WoT     = (unsigned short*)(ws + 16384 + 4 * SZ);
    unsigned short* xh      = (unsigned short*)(ws + 16384 + 4 * SZ + WZ);
    unsigned short* xm      = (unsigned short*)(ws + 16384 + 5 * SZ + WZ);
    unsigned short* xl      = (unsigned short*)(ws + 16384 + 6 * SZ + WZ);
    unsigned short* WTh     = (unsigned short*)(ws + 16384 + 7 * SZ + WZ);       // 3 stacked
    unsigned short* WTm     = (unsigned short*)(ws + 16384 + 7 * SZ + 4 * WZ);
    unsigned short* WTl     = (unsigned short*)(ws + 16384 + 7 * SZ + 7 * WZ);
    float* out = (float*)d_out;

    gates_kernel<<<dim3(NROWS / GROWS), dim3(256), 0, stream>>>(
        x, gW1, gb1, gg, gbe, gW2, gb2, gW3, gb3,
        cW1, cb1, cg, cbe, cW2, cb2, cW3, cb3, Tp);

    split_x_kernel<<<dim3(NROWS * EMB / 1024), dim3(256), 0, stream>>>(x, xh, xm, xl);

    split_wt_kernel<<<dim3(EMB / 64, EMB / 64, 3), dim3(256), 0, stream>>>(
        Wq, Wk, Wv, WTh, WTm, WTl);

    qkv_mfma_lif_kernel<<<dim3(1536), dim3(256), 0, stream>>>(
        xh, xm, xl, WTh, WTm, WTl, aq, bq, ak, bk, av, bv, Tp,
        q_sum, k_sum, v_mean);

    wot_prep<<<dim3(EMB / 64, EMB / 64), dim3(256), 0, stream>>>(Wo, WoT);

    attn_mfma_kernel<<<dim3(SEQ / 64, 8, 4), dim3(256), 0, stream>>>(
        q_sum, k_sum, v_mean, attn_bf);

    out_gemm_kernel<<<dim3(EMB / 64, NROWS / 64), dim3(256), 0, stream>>>(
        attn_bf, WoT, bo, out);
}